// Round 1
// baseline (1044.865 us; speedup 1.0000x reference)
//
#include <hip/hip_runtime.h>

#define HID 128
#define EDGE_DIM 10
#define BN_EPS 1e-5f
#define EPW 8   // edges per wave in edge kernels

// ---- order-preserving float<->uint map for atomicMax on floats ----
__device__ __forceinline__ unsigned int fmap(float f) {
    unsigned int u = __float_as_uint(f);
    return (u & 0x80000000u) ? ~u : (u | 0x80000000u);
}
__device__ __forceinline__ float funmap(unsigned int u) {
    return __uint_as_float((u & 0x80000000u) ? (u ^ 0x80000000u) : ~u);
}

// ---- init: amax = mapped(-inf)=0, denom = 0, BN sums = 0 ----
__global__ void init_kernel(unsigned int* __restrict__ amax, float* __restrict__ denom,
                            float* __restrict__ sums, float* __restrict__ sumsq, int N) {
    int i = blockIdx.x * 256 + threadIdx.x;
    if (i < N) { amax[i] = 0u; denom[i] = 0.f; }
    if (i < HID) { sums[i] = 0.f; sumsq[i] = 0.f; }
}

// ---- fused node projections: out = x @ W.T + b  (blockIdx.y picks matrix) ----
__global__ __launch_bounds__(256) void proj_kernel(
    const float* __restrict__ x,
    const float* __restrict__ W0, const float* __restrict__ b0,
    const float* __restrict__ W1, const float* __restrict__ b1,
    const float* __restrict__ W2, const float* __restrict__ b2,
    const float* __restrict__ W3, const float* __restrict__ b3,
    float* __restrict__ o0, float* __restrict__ o1,
    float* __restrict__ o2, float* __restrict__ o3, int N)
{
    const int which = blockIdx.y;
    const float* W    = (which == 0) ? W0 : (which == 1) ? W1 : (which == 2) ? W2 : W3;
    const float* bias = (which == 0) ? b0 : (which == 1) ? b1 : (which == 2) ? b2 : b3;
    float* out        = (which == 0) ? o0 : (which == 1) ? o1 : (which == 2) ? o2 : o3;

    const int n0 = blockIdx.x * 64;
    const int t  = threadIdx.x;
    const int tc = t & 31;   // 32 col-groups * 4 cols = 128
    const int tr = t >> 5;   // 8 row-groups * 8 rows = 64

    __shared__ float xs[64][16];
    __shared__ float wsm[16][132];   // [k][c], padded to kill write conflicts

    float acc[8][4];
    #pragma unroll
    for (int i = 0; i < 8; ++i)
        #pragma unroll
        for (int j = 0; j < 4; ++j) acc[i][j] = 0.f;

    for (int kt = 0; kt < 8; ++kt) {
        const int k0 = kt * 16;
        #pragma unroll
        for (int i = 0; i < 4; ++i) {
            int idx = i * 256 + t;
            int r = idx >> 4, kk = idx & 15;
            xs[r][kk] = (n0 + r < N) ? x[(size_t)(n0 + r) * HID + k0 + kk] : 0.f;
        }
        #pragma unroll
        for (int i = 0; i < 8; ++i) {
            int idx = i * 256 + t;
            int c = idx >> 4, kk = idx & 15;
            wsm[kk][c] = W[(size_t)c * HID + k0 + kk];
        }
        __syncthreads();
        #pragma unroll
        for (int kk = 0; kk < 16; kk += 2) {
            float4 w0 = *(const float4*)&wsm[kk][tc * 4];
            float4 w1 = *(const float4*)&wsm[kk + 1][tc * 4];
            #pragma unroll
            for (int i = 0; i < 8; ++i) {
                float2 a = *(const float2*)&xs[tr * 8 + i][kk];
                acc[i][0] += a.x * w0.x + a.y * w1.x;
                acc[i][1] += a.x * w0.y + a.y * w1.y;
                acc[i][2] += a.x * w0.z + a.y * w1.z;
                acc[i][3] += a.x * w0.w + a.y * w1.w;
            }
        }
        __syncthreads();
    }

    float4 b4 = *(const float4*)&bias[tc * 4];
    #pragma unroll
    for (int i = 0; i < 8; ++i) {
        int row = n0 + tr * 8 + i;
        if (row < N) {
            float4 o;
            o.x = acc[i][0] + b4.x; o.y = acc[i][1] + b4.y;
            o.z = acc[i][2] + b4.z; o.w = acc[i][3] + b4.w;
            *(float4*)&out[(size_t)row * HID + tc * 4] = o;
        }
    }
}

// ---- per-edge attention score + segment max ----
__global__ __launch_bounds__(256) void alpha_kernel(
    const int* __restrict__ ei, const float* __restrict__ ea,
    const float* __restrict__ We,
    const float* __restrict__ q_all, const float* __restrict__ k_all,
    float* __restrict__ alpha, unsigned int* __restrict__ amax, int E)
{
    const int wave = blockIdx.x * 4 + (threadIdx.x >> 6);
    const int lane = threadIdx.x & 63;
    const int d0 = lane * 2;

    float w0[EDGE_DIM], w1[EDGE_DIM];
    #pragma unroll
    for (int j = 0; j < EDGE_DIM; ++j) {
        w0[j] = We[d0 * EDGE_DIM + j];
        w1[j] = We[(d0 + 1) * EDGE_DIM + j];
    }

    int eBeg = wave * EPW;
    int eEnd = min(eBeg + EPW, E);
    for (int e = eBeg; e < eEnd; ++e) {
        int src = ei[e];
        int dst = ei[E + e];
        float eav = (lane < EDGE_DIM) ? ea[(size_t)e * EDGE_DIM + lane] : 0.f;
        float f0 = 0.f, f1 = 0.f;
        #pragma unroll
        for (int j = 0; j < EDGE_DIM; ++j) {
            float a = __shfl(eav, j, 64);
            f0 += a * w0[j];
            f1 += a * w1[j];
        }
        float2 q2 = ((const float2*)q_all)[(size_t)dst * 64 + lane];
        float2 k2 = ((const float2*)k_all)[(size_t)src * 64 + lane];
        float p = q2.x * (k2.x + f0) + q2.y * (k2.y + f1);
        #pragma unroll
        for (int off = 32; off; off >>= 1) p += __shfl_xor(p, off, 64);
        if (lane == 0) {
            float al = p * 0.08838834764831845f;  // 1/sqrt(128)
            alpha[e] = al;
            atomicMax(&amax[dst], fmap(al));
        }
    }
}

// ---- exp(alpha - max) + segment denom ----
__global__ void exp_kernel(const int* __restrict__ ei, float* __restrict__ alpha,
                           const unsigned int* __restrict__ amax,
                           float* __restrict__ denom, int E) {
    int e = blockIdx.x * 256 + threadIdx.x;
    if (e >= E) return;
    int dst = ei[E + e];
    float m = funmap(amax[dst]);
    float ex = expf(alpha[e] - m);
    alpha[e] = ex;
    atomicAdd(&denom[dst], ex);
}

// ---- weighted aggregation: out[dst] += w * (v[src] + e) ----
__global__ __launch_bounds__(256) void agg_kernel(
    const int* __restrict__ ei, const float* __restrict__ ea,
    const float* __restrict__ We,
    const float* __restrict__ v_all, const float* __restrict__ exw,
    const float* __restrict__ denom, float* __restrict__ out, int E)
{
    const int wave = blockIdx.x * 4 + (threadIdx.x >> 6);
    const int lane = threadIdx.x & 63;
    const int d0 = lane * 2;

    float w0[EDGE_DIM], w1[EDGE_DIM];
    #pragma unroll
    for (int j = 0; j < EDGE_DIM; ++j) {
        w0[j] = We[d0 * EDGE_DIM + j];
        w1[j] = We[(d0 + 1) * EDGE_DIM + j];
    }

    int eBeg = wave * EPW;
    int eEnd = min(eBeg + EPW, E);
    for (int e = eBeg; e < eEnd; ++e) {
        int src = ei[e];
        int dst = ei[E + e];
        float eav = (lane < EDGE_DIM) ? ea[(size_t)e * EDGE_DIM + lane] : 0.f;
        float f0 = 0.f, f1 = 0.f;
        #pragma unroll
        for (int j = 0; j < EDGE_DIM; ++j) {
            float a = __shfl(eav, j, 64);
            f0 += a * w0[j];
            f1 += a * w1[j];
        }
        float w = exw[e] / denom[dst];
        float2 v2 = ((const float2*)v_all)[(size_t)src * 64 + lane];
        atomicAdd(&out[(size_t)dst * HID + d0],     w * (v2.x + f0));
        atomicAdd(&out[(size_t)dst * HID + d0 + 1], w * (v2.y + f1));
    }
}

// ---- BN stats: per-feature sum / sumsq of relu(out) ----
__global__ __launch_bounds__(256) void bnstats_kernel(const float* __restrict__ out,
                                                      float* __restrict__ sums,
                                                      float* __restrict__ sumsq, int N) {
    int f = threadIdx.x & 127;
    int half = threadIdx.x >> 7;
    float s = 0.f, s2 = 0.f;
    for (int r = blockIdx.x * 2 + half; r < N; r += gridDim.x * 2) {
        float h = out[(size_t)r * HID + f];
        h = h > 0.f ? h : 0.f;
        s += h; s2 += h * h;
    }
    __shared__ float ls[256], ls2[256];
    ls[threadIdx.x] = s; ls2[threadIdx.x] = s2;
    __syncthreads();
    if (half == 0) {
        s = ls[f] + ls[f + 128];
        s2 = ls2[f] + ls2[f + 128];
        atomicAdd(&sums[f], s);
        atomicAdd(&sumsq[f], s2);
    }
}

// ---- fold BN stats into per-feature scale/shift ----
__global__ void bnscale_kernel(const float* __restrict__ sums, const float* __restrict__ sumsq,
                               const float* __restrict__ gamma, const float* __restrict__ beta,
                               float* __restrict__ scale, float* __restrict__ shift, int N) {
    int f = threadIdx.x;
    if (f < HID) {
        float invN = 1.f / (float)N;
        float m = sums[f] * invN;
        float var = sumsq[f] * invN - m * m;
        float s = gamma[f] * rsqrtf(var + BN_EPS);
        scale[f] = s;
        shift[f] = beta[f] - m * s;
    }
}

// ---- apply: out = relu(out)*scale + shift (in place, float4) ----
__global__ __launch_bounds__(256) void bnapply_kernel(float* __restrict__ out,
                                                      const float* __restrict__ scale,
                                                      const float* __restrict__ shift, int N) {
    int idx = blockIdx.x * 256 + threadIdx.x;
    int total = N * (HID / 4);
    if (idx >= total) return;
    int f4 = (idx & 31) * 4;
    float4 v = ((const float4*)out)[idx];
    float4 o;
    float h;
    h = v.x > 0.f ? v.x : 0.f; o.x = h * scale[f4 + 0] + shift[f4 + 0];
    h = v.y > 0.f ? v.y : 0.f; o.y = h * scale[f4 + 1] + shift[f4 + 1];
    h = v.z > 0.f ? v.z : 0.f; o.z = h * scale[f4 + 2] + shift[f4 + 2];
    h = v.w > 0.f ? v.w : 0.f; o.w = h * scale[f4 + 3] + shift[f4 + 3];
    ((float4*)out)[idx] = o;
}

extern "C" void kernel_launch(void* const* d_in, const int* in_sizes, int n_in,
                              void* d_out, int out_size, void* d_ws, size_t ws_size,
                              hipStream_t stream) {
    const float* x     = (const float*)d_in[0];
    const int*   ei    = (const int*)d_in[1];
    const float* ea    = (const float*)d_in[2];
    const float* Wq    = (const float*)d_in[3];
    const float* bq    = (const float*)d_in[4];
    const float* Wk    = (const float*)d_in[5];
    const float* bk    = (const float*)d_in[6];
    const float* Wv    = (const float*)d_in[7];
    const float* bv    = (const float*)d_in[8];
    const float* We    = (const float*)d_in[9];
    const float* Wskip = (const float*)d_in[10];
    const float* bskip = (const float*)d_in[11];
    const float* gamma = (const float*)d_in[12];
    const float* beta  = (const float*)d_in[13];
    float* out = (float*)d_out;

    const int N = in_sizes[0] / HID;
    const int E = in_sizes[2] / EDGE_DIM;
    const size_t NH = (size_t)N * HID;

    float* ws = (float*)d_ws;
    float* q_all = ws;
    float* k_all = ws + NH;
    float* v_all = ws + 2 * NH;
    float* alpha = ws + 3 * NH;                       // E floats (raw score, then exp)
    unsigned int* amax = (unsigned int*)(alpha + E);  // N uints
    float* denom = (float*)(amax + N);                // N floats
    float* sums  = denom + N;                         // 128
    float* sumsq = sums + HID;                        // 128
    float* scale = sumsq + HID;                       // 128
    float* shift = scale + HID;                       // 128

    init_kernel<<<(N + 255) / 256, 256, 0, stream>>>(amax, denom, sums, sumsq, N);

    dim3 pg((N + 63) / 64, 4);
    proj_kernel<<<pg, 256, 0, stream>>>(x, Wq, bq, Wk, bk, Wv, bv, Wskip, bskip,
                                        q_all, k_all, v_all, out, N);

    int edgeBlocks = (E + EPW * 4 - 1) / (EPW * 4);
    alpha_kernel<<<edgeBlocks, 256, 0, stream>>>(ei, ea, We, q_all, k_all, alpha, amax, E);
    exp_kernel<<<(E + 255) / 256, 256, 0, stream>>>(ei, alpha, amax, denom, E);
    agg_kernel<<<edgeBlocks, 256, 0, stream>>>(ei, ea, We, v_all, alpha, denom, out, E);

    bnstats_kernel<<<1024, 256, 0, stream>>>(out, sums, sumsq, N);
    bnscale_kernel<<<1, 128, 0, stream>>>(sums, sumsq, gamma, beta, scale, shift, N);
    bnapply_kernel<<<(N * (HID / 4) + 255) / 256, 256, 0, stream>>>(out, scale, shift, N);
}

// Round 2
// 602.561 us; speedup vs baseline: 1.7340x; 1.7340x over previous
//
#include <hip/hip_runtime.h>

#define HID 128
#define EDGE_DIM 10
#define BN_EPS 1e-5f

// ---- init: zero degree counters and BN sums ----
__global__ void init_kernel(int* __restrict__ deg, float* __restrict__ sums,
                            float* __restrict__ sumsq, int N) {
    int i = blockIdx.x * 256 + threadIdx.x;
    if (i < N) deg[i] = 0;
    if (i < HID) { sums[i] = 0.f; sumsq[i] = 0.f; }
}

// ---- fused node projections: out = x @ W.T + b  (blockIdx.y picks matrix) ----
__global__ __launch_bounds__(256) void proj_kernel(
    const float* __restrict__ x,
    const float* __restrict__ W0, const float* __restrict__ b0,
    const float* __restrict__ W1, const float* __restrict__ b1,
    const float* __restrict__ W2, const float* __restrict__ b2,
    const float* __restrict__ W3, const float* __restrict__ b3,
    float* __restrict__ o0, float* __restrict__ o1,
    float* __restrict__ o2, float* __restrict__ o3, int N)
{
    const int which = blockIdx.y;
    const float* W    = (which == 0) ? W0 : (which == 1) ? W1 : (which == 2) ? W2 : W3;
    const float* bias = (which == 0) ? b0 : (which == 1) ? b1 : (which == 2) ? b2 : b3;
    float* out        = (which == 0) ? o0 : (which == 1) ? o1 : (which == 2) ? o2 : o3;

    const int n0 = blockIdx.x * 64;
    const int t  = threadIdx.x;
    const int tc = t & 31;   // 32 col-groups * 4 cols = 128
    const int tr = t >> 5;   // 8 row-groups * 8 rows = 64

    __shared__ float xs[64][16];
    __shared__ float wsm[16][132];   // [k][c], padded

    float acc[8][4];
    #pragma unroll
    for (int i = 0; i < 8; ++i)
        #pragma unroll
        for (int j = 0; j < 4; ++j) acc[i][j] = 0.f;

    for (int kt = 0; kt < 8; ++kt) {
        const int k0 = kt * 16;
        #pragma unroll
        for (int i = 0; i < 4; ++i) {
            int idx = i * 256 + t;
            int r = idx >> 4, kk = idx & 15;
            xs[r][kk] = (n0 + r < N) ? x[(size_t)(n0 + r) * HID + k0 + kk] : 0.f;
        }
        #pragma unroll
        for (int i = 0; i < 8; ++i) {
            int idx = i * 256 + t;
            int c = idx >> 4, kk = idx & 15;
            wsm[kk][c] = W[(size_t)c * HID + k0 + kk];
        }
        __syncthreads();
        #pragma unroll
        for (int kk = 0; kk < 16; kk += 2) {
            float4 w0 = *(const float4*)&wsm[kk][tc * 4];
            float4 w1 = *(const float4*)&wsm[kk + 1][tc * 4];
            #pragma unroll
            for (int i = 0; i < 8; ++i) {
                float2 a = *(const float2*)&xs[tr * 8 + i][kk];
                acc[i][0] += a.x * w0.x + a.y * w1.x;
                acc[i][1] += a.x * w0.y + a.y * w1.y;
                acc[i][2] += a.x * w0.z + a.y * w1.z;
                acc[i][3] += a.x * w0.w + a.y * w1.w;
            }
        }
        __syncthreads();
    }

    float4 b4 = *(const float4*)&bias[tc * 4];
    #pragma unroll
    for (int i = 0; i < 8; ++i) {
        int row = n0 + tr * 8 + i;
        if (row < N) {
            float4 o;
            o.x = acc[i][0] + b4.x; o.y = acc[i][1] + b4.y;
            o.z = acc[i][2] + b4.z; o.w = acc[i][3] + b4.w;
            *(float4*)&out[(size_t)row * HID + tc * 4] = o;
        }
    }
}

// ---- CSR build step 1: in-degree count ----
__global__ void degree_kernel(const int* __restrict__ ei, int* __restrict__ deg, int E) {
    int e = blockIdx.x * 256 + threadIdx.x;
    if (e < E) atomicAdd(&deg[ei[E + e]], 1);
}

// ---- CSR build step 2: exclusive scan (single 1024-thread block) ----
// deg[] is overwritten with the exclusive prefix (doubles as scatter cursor).
__global__ __launch_bounds__(1024) void scan_kernel(int* __restrict__ deg,
                                                    int* __restrict__ rowptr, int N) {
    __shared__ int tile[1024];
    __shared__ int carry;
    if (threadIdx.x == 0) carry = 0;
    __syncthreads();
    for (int base = 0; base < N; base += 1024) {
        int i = base + threadIdx.x;
        int v = (i < N) ? deg[i] : 0;
        tile[threadIdx.x] = v;
        __syncthreads();
        for (int off = 1; off < 1024; off <<= 1) {
            int t = (threadIdx.x >= off) ? tile[threadIdx.x - off] : 0;
            __syncthreads();
            tile[threadIdx.x] += t;
            __syncthreads();
        }
        int excl = carry + tile[threadIdx.x] - v;
        if (i < N) { rowptr[i] = excl; deg[i] = excl; }
        __syncthreads();
        if (threadIdx.x == 0) carry += tile[1023];
        __syncthreads();
    }
    if (threadIdx.x == 0) rowptr[N] = carry;
}

// ---- CSR build step 3: scatter edge ids into dst buckets ----
__global__ void scatter_kernel(const int* __restrict__ ei, int* __restrict__ cursor,
                               int* __restrict__ csr_eid, int E) {
    int e = blockIdx.x * 256 + threadIdx.x;
    if (e < E) {
        int dst = ei[E + e];
        int pos = atomicAdd(&cursor[dst], 1);
        csr_eid[pos] = e;
    }
}

// ---- fused attention: per dst node, online softmax over incoming edges ----
// one wave per node; out[node] += softmax-weighted sum of (v[src]+e)
__global__ __launch_bounds__(256) void attn_kernel(
    const int* __restrict__ ei, const float* __restrict__ ea,
    const float* __restrict__ We,
    const float* __restrict__ q_all, const float* __restrict__ k_all,
    const float* __restrict__ v_all,
    const int* __restrict__ rowptr, const int* __restrict__ csr_eid,
    float* __restrict__ out, int N, int E)
{
    const int node = blockIdx.x * 4 + (threadIdx.x >> 6);
    if (node >= N) return;
    const int lane = threadIdx.x & 63;
    const int d0 = lane * 2;

    // cache this lane's 2 rows of We
    float w0[EDGE_DIM], w1[EDGE_DIM];
    #pragma unroll
    for (int j = 0; j < EDGE_DIM; ++j) {
        w0[j] = We[d0 * EDGE_DIM + j];
        w1[j] = We[(d0 + 1) * EDGE_DIM + j];
    }

    const int p0 = rowptr[node];
    const int p1 = rowptr[node + 1];
    if (p0 == p1) return;   // no incoming edges: agg = 0, out keeps skip

    float2 q2 = ((const float2*)q_all)[(size_t)node * 64 + lane];

    float m = -INFINITY, l = 0.f, a0 = 0.f, a1 = 0.f;
    for (int p = p0; p < p1; ++p) {
        int eid = csr_eid[p];
        int src = ei[eid];
        float eav = (lane < EDGE_DIM) ? ea[(size_t)eid * EDGE_DIM + lane] : 0.f;
        float f0 = 0.f, f1 = 0.f;
        #pragma unroll
        for (int j = 0; j < EDGE_DIM; ++j) {
            float a = __shfl(eav, j, 64);
            f0 += a * w0[j];
            f1 += a * w1[j];
        }
        float2 k2 = ((const float2*)k_all)[(size_t)src * 64 + lane];
        float s = q2.x * (k2.x + f0) + q2.y * (k2.y + f1);
        #pragma unroll
        for (int off = 32; off; off >>= 1) s += __shfl_xor(s, off, 64);
        s *= 0.08838834764831845f;  // 1/sqrt(128)

        float2 v2 = ((const float2*)v_all)[(size_t)src * 64 + lane];
        float mnew = fmaxf(m, s);
        float c   = expf(m - mnew);   // 0 on first edge (m = -inf)
        float pij = expf(s - mnew);
        l  = l  * c + pij;
        a0 = a0 * c + pij * (v2.x + f0);
        a1 = a1 * c + pij * (v2.y + f1);
        m = mnew;
    }

    float inv = 1.f / l;
    float2* o = (float2*)&out[(size_t)node * HID + d0];
    float2 cur = *o;                  // skip projection already there
    cur.x += a0 * inv;
    cur.y += a1 * inv;
    *o = cur;
}

// ---- BN stats: per-feature sum / sumsq of relu(out) ----
__global__ __launch_bounds__(256) void bnstats_kernel(const float* __restrict__ out,
                                                      float* __restrict__ sums,
                                                      float* __restrict__ sumsq, int N) {
    int f = threadIdx.x & 127;
    int half = threadIdx.x >> 7;
    float s = 0.f, s2 = 0.f;
    for (int r = blockIdx.x * 2 + half; r < N; r += gridDim.x * 2) {
        float h = out[(size_t)r * HID + f];
        h = h > 0.f ? h : 0.f;
        s += h; s2 += h * h;
    }
    __shared__ float ls[256], ls2[256];
    ls[threadIdx.x] = s; ls2[threadIdx.x] = s2;
    __syncthreads();
    if (half == 0) {
        s = ls[f] + ls[f + 128];
        s2 = ls2[f] + ls2[f + 128];
        atomicAdd(&sums[f], s);
        atomicAdd(&sumsq[f], s2);
    }
}

// ---- fold BN stats into per-feature scale/shift ----
__global__ void bnscale_kernel(const float* __restrict__ sums, const float* __restrict__ sumsq,
                               const float* __restrict__ gamma, const float* __restrict__ beta,
                               float* __restrict__ scale, float* __restrict__ shift, int N) {
    int f = threadIdx.x;
    if (f < HID) {
        float invN = 1.f / (float)N;
        float m = sums[f] * invN;
        float var = sumsq[f] * invN - m * m;
        float s = gamma[f] * rsqrtf(var + BN_EPS);
        scale[f] = s;
        shift[f] = beta[f] - m * s;
    }
}

// ---- apply: out = relu(out)*scale + shift (in place, float4) ----
__global__ __launch_bounds__(256) void bnapply_kernel(float* __restrict__ out,
                                                      const float* __restrict__ scale,
                                                      const float* __restrict__ shift, int N) {
    int idx = blockIdx.x * 256 + threadIdx.x;
    int total = N * (HID / 4);
    if (idx >= total) return;
    int f4 = (idx & 31) * 4;
    float4 v = ((const float4*)out)[idx];
    float4 o;
    float h;
    h = v.x > 0.f ? v.x : 0.f; o.x = h * scale[f4 + 0] + shift[f4 + 0];
    h = v.y > 0.f ? v.y : 0.f; o.y = h * scale[f4 + 1] + shift[f4 + 1];
    h = v.z > 0.f ? v.z : 0.f; o.z = h * scale[f4 + 2] + shift[f4 + 2];
    h = v.w > 0.f ? v.w : 0.f; o.w = h * scale[f4 + 3] + shift[f4 + 3];
    ((float4*)out)[idx] = o;
}

extern "C" void kernel_launch(void* const* d_in, const int* in_sizes, int n_in,
                              void* d_out, int out_size, void* d_ws, size_t ws_size,
                              hipStream_t stream) {
    const float* x     = (const float*)d_in[0];
    const int*   ei    = (const int*)d_in[1];
    const float* ea    = (const float*)d_in[2];
    const float* Wq    = (const float*)d_in[3];
    const float* bq    = (const float*)d_in[4];
    const float* Wk    = (const float*)d_in[5];
    const float* bk    = (const float*)d_in[6];
    const float* Wv    = (const float*)d_in[7];
    const float* bv    = (const float*)d_in[8];
    const float* We    = (const float*)d_in[9];
    const float* Wskip = (const float*)d_in[10];
    const float* bskip = (const float*)d_in[11];
    const float* gamma = (const float*)d_in[12];
    const float* beta  = (const float*)d_in[13];
    float* out = (float*)d_out;

    const int N = in_sizes[0] / HID;
    const int E = in_sizes[2] / EDGE_DIM;
    const size_t NH = (size_t)N * HID;

    float* ws = (float*)d_ws;
    float* q_all = ws;
    float* k_all = ws + NH;
    float* v_all = ws + 2 * NH;
    int* deg     = (int*)(ws + 3 * NH);   // N ints; becomes scatter cursor
    int* rowptr  = deg + N;               // N+1 ints
    int* csr_eid = rowptr + N + 1;        // E ints
    float* sums  = (float*)(csr_eid + E); // 128
    float* sumsq = sums + HID;            // 128
    float* scale = sumsq + HID;           // 128
    float* shift = scale + HID;           // 128

    init_kernel<<<(N + 255) / 256, 256, 0, stream>>>(deg, sums, sumsq, N);

    dim3 pg((N + 63) / 64, 4);
    proj_kernel<<<pg, 256, 0, stream>>>(x, Wq, bq, Wk, bk, Wv, bv, Wskip, bskip,
                                        q_all, k_all, v_all, out, N);

    degree_kernel<<<(E + 255) / 256, 256, 0, stream>>>(ei, deg, E);
    scan_kernel<<<1, 1024, 0, stream>>>(deg, rowptr, N);
    scatter_kernel<<<(E + 255) / 256, 256, 0, stream>>>(ei, deg, csr_eid, E);

    attn_kernel<<<(N + 3) / 4, 256, 0, stream>>>(ei, ea, We, q_all, k_all, v_all,
                                                 rowptr, csr_eid, out, N, E);

    bnstats_kernel<<<1024, 256, 0, stream>>>(out, sums, sumsq, N);
    bnscale_kernel<<<1, 128, 0, stream>>>(sums, sumsq, gamma, beta, scale, shift, N);
    bnapply_kernel<<<(N * (HID / 4) + 255) / 256, 256, 0, stream>>>(out, scale, shift, N);
}

// Round 3
// 466.769 us; speedup vs baseline: 2.2385x; 1.2909x over previous
//
#include <hip/hip_runtime.h>

#define HID 128
#define EDGE_DIM 10
#define BN_EPS 1e-5f
#define ATT_SCALE 0.08838834764831845f  // 1/sqrt(128)

typedef unsigned short ushort_t;

__device__ __forceinline__ float b2f(ushort_t u) {
    return __uint_as_float(((unsigned)u) << 16);
}
__device__ __forceinline__ ushort_t f2b(float f) {   // RNE
    unsigned u = __float_as_uint(f);
    return (ushort_t)((u + 0x7FFFu + ((u >> 16) & 1u)) >> 16);
}

// ---- init: zero degree counters and BN sums ----
__global__ void init_kernel(int* __restrict__ deg, float* __restrict__ sums,
                            float* __restrict__ sumsq, int N) {
    int i = blockIdx.x * 256 + threadIdx.x;
    if (i < N) deg[i] = 0;
    if (i < HID) { sums[i] = 0.f; sumsq[i] = 0.f; }
}

// ---- fused node projections (blockIdx.y picks matrix) ----
// which 0: q (fp32)   1: k (bf16 -> kv[..][0:128])   2: v (bf16 -> kv[..][128:256])
// which 3: skip (fp32 -> out)
__global__ __launch_bounds__(256) void proj_kernel(
    const float* __restrict__ x,
    const float* __restrict__ W0, const float* __restrict__ b0,
    const float* __restrict__ W1, const float* __restrict__ b1,
    const float* __restrict__ W2, const float* __restrict__ b2,
    const float* __restrict__ W3, const float* __restrict__ b3,
    float* __restrict__ q_all, ushort_t* __restrict__ kv,
    float* __restrict__ out, int N)
{
    const int which = blockIdx.y;
    const float* W    = (which == 0) ? W0 : (which == 1) ? W1 : (which == 2) ? W2 : W3;
    const float* bias = (which == 0) ? b0 : (which == 1) ? b1 : (which == 2) ? b2 : b3;

    const int n0 = blockIdx.x * 64;
    const int t  = threadIdx.x;
    const int tc = t & 31;   // 32 col-groups * 4 cols = 128
    const int tr = t >> 5;   // 8 row-groups * 8 rows = 64

    __shared__ float xs[64][16];
    __shared__ float wsm[16][132];

    float acc[8][4];
    #pragma unroll
    for (int i = 0; i < 8; ++i)
        #pragma unroll
        for (int j = 0; j < 4; ++j) acc[i][j] = 0.f;

    for (int kt = 0; kt < 8; ++kt) {
        const int k0 = kt * 16;
        #pragma unroll
        for (int i = 0; i < 4; ++i) {
            int idx = i * 256 + t;
            int r = idx >> 4, kk = idx & 15;
            xs[r][kk] = (n0 + r < N) ? x[(size_t)(n0 + r) * HID + k0 + kk] : 0.f;
        }
        #pragma unroll
        for (int i = 0; i < 8; ++i) {
            int idx = i * 256 + t;
            int c = idx >> 4, kk = idx & 15;
            wsm[kk][c] = W[(size_t)c * HID + k0 + kk];
        }
        __syncthreads();
        #pragma unroll
        for (int kk = 0; kk < 16; kk += 2) {
            float4 w0 = *(const float4*)&wsm[kk][tc * 4];
            float4 w1 = *(const float4*)&wsm[kk + 1][tc * 4];
            #pragma unroll
            for (int i = 0; i < 8; ++i) {
                float2 a = *(const float2*)&xs[tr * 8 + i][kk];
                acc[i][0] += a.x * w0.x + a.y * w1.x;
                acc[i][1] += a.x * w0.y + a.y * w1.y;
                acc[i][2] += a.x * w0.z + a.y * w1.z;
                acc[i][3] += a.x * w0.w + a.y * w1.w;
            }
        }
        __syncthreads();
    }

    float4 b4 = *(const float4*)&bias[tc * 4];
    #pragma unroll
    for (int i = 0; i < 8; ++i) {
        int row = n0 + tr * 8 + i;
        if (row >= N) continue;
        float vx = acc[i][0] + b4.x, vy = acc[i][1] + b4.y;
        float vz = acc[i][2] + b4.z, vw = acc[i][3] + b4.w;
        if (which == 0) {
            *(float4*)&q_all[(size_t)row * HID + tc * 4] = make_float4(vx, vy, vz, vw);
        } else if (which == 3) {
            *(float4*)&out[(size_t)row * HID + tc * 4] = make_float4(vx, vy, vz, vw);
        } else {
            ushort_t* dst = kv + (size_t)row * 256 + (which == 2 ? 128 : 0) + tc * 4;
            ushort4 p;
            p.x = f2b(vx); p.y = f2b(vy); p.z = f2b(vz); p.w = f2b(vw);
            *(ushort4*)dst = p;
        }
    }
}

// ---- CSR build step 1: in-degree count ----
__global__ void degree_kernel(const int* __restrict__ ei, int* __restrict__ deg, int E) {
    int e = blockIdx.x * 256 + threadIdx.x;
    if (e < E) atomicAdd(&deg[ei[E + e]], 1);
}

// ---- CSR build: 3-phase parallel exclusive scan ----
__global__ __launch_bounds__(256) void scan1_kernel(const int* __restrict__ deg,
                                                    int* __restrict__ rowptr,
                                                    int* __restrict__ partials, int N) {
    int i = blockIdx.x * 256 + threadIdx.x;
    int v = (i < N) ? deg[i] : 0;
    __shared__ int sm[256];
    sm[threadIdx.x] = v;
    __syncthreads();
    for (int off = 1; off < 256; off <<= 1) {
        int t = (threadIdx.x >= off) ? sm[threadIdx.x - off] : 0;
        __syncthreads();
        sm[threadIdx.x] += t;
        __syncthreads();
    }
    if (i < N) rowptr[i] = sm[threadIdx.x] - v;   // block-local exclusive
    if (threadIdx.x == 255) partials[blockIdx.x] = sm[255];
}

__global__ __launch_bounds__(256) void scan2_kernel(int* __restrict__ partials,
                                                    int* __restrict__ rowptr, int nb, int N) {
    __shared__ int sm[256];
    int v = (threadIdx.x < nb) ? partials[threadIdx.x] : 0;
    sm[threadIdx.x] = v;
    __syncthreads();
    for (int off = 1; off < 256; off <<= 1) {
        int t = (threadIdx.x >= off) ? sm[threadIdx.x - off] : 0;
        __syncthreads();
        sm[threadIdx.x] += t;
        __syncthreads();
    }
    if (threadIdx.x < nb) partials[threadIdx.x] = sm[threadIdx.x] - v;   // exclusive
    if (threadIdx.x == 255) rowptr[N] = sm[255];
}

__global__ __launch_bounds__(256) void scan3_kernel(int* __restrict__ rowptr,
                                                    int* __restrict__ deg,
                                                    const int* __restrict__ partials, int N) {
    int i = blockIdx.x * 256 + threadIdx.x;
    if (i < N) {
        int r = rowptr[i] + partials[blockIdx.x];
        rowptr[i] = r;
        deg[i] = r;   // scatter cursor
    }
}

// ---- CSR build step 3: scatter (src, eid) pairs into dst buckets ----
__global__ void scatter_kernel(const int* __restrict__ ei, int* __restrict__ cursor,
                               int2* __restrict__ csr_se, int E) {
    int e = blockIdx.x * 256 + threadIdx.x;
    if (e < E) {
        int src = ei[e];
        int dst = ei[E + e];
        int pos = atomicAdd(&cursor[dst], 1);
        csr_se[pos] = make_int2(src, e);
    }
}

// ---- fused attention: one wave per dst node, no-max softmax (scores tiny) ----
__global__ __launch_bounds__(256) void attn_kernel(
    const float* __restrict__ ea, const float* __restrict__ We,
    const float* __restrict__ q_all, const ushort_t* __restrict__ kv,
    const int* __restrict__ rowptr, const int2* __restrict__ csr_se,
    float* __restrict__ out, int N)
{
    const int node = blockIdx.x * 4 + (threadIdx.x >> 6);
    if (node >= N) return;
    const int lane = threadIdx.x & 63;
    const int d0 = lane * 2;

    float w0[EDGE_DIM], w1[EDGE_DIM];
    #pragma unroll
    for (int j = 0; j < EDGE_DIM; ++j) {
        w0[j] = We[d0 * EDGE_DIM + j];
        w1[j] = We[(d0 + 1) * EDGE_DIM + j];
    }

    const int p0 = rowptr[node];
    const int p1 = rowptr[node + 1];
    if (p0 == p1) return;

    float2 q2 = ((const float2*)q_all)[(size_t)node * 64 + lane];

    float l = 0.f, A0 = 0.f, A1 = 0.f;
    int p = p0;
    for (; p + 2 <= p1; p += 2) {
        int2 se0 = csr_se[p];
        int2 se1 = csr_se[p + 1];
        float ev0 = (lane < EDGE_DIM) ? ea[(size_t)se0.y * EDGE_DIM + lane] : 0.f;
        float ev1 = (lane < EDGE_DIM) ? ea[(size_t)se1.y * EDGE_DIM + lane] : 0.f;
        float f00 = 0.f, f01 = 0.f, f10 = 0.f, f11 = 0.f;
        #pragma unroll
        for (int j = 0; j < EDGE_DIM; ++j) {
            float a = __shfl(ev0, j, 64);
            float b = __shfl(ev1, j, 64);
            f00 += a * w0[j]; f01 += a * w1[j];
            f10 += b * w0[j]; f11 += b * w1[j];
        }
        const ushort2* r0 = (const ushort2*)(kv + (size_t)se0.x * 256);
        const ushort2* r1 = (const ushort2*)(kv + (size_t)se1.x * 256);
        ushort2 k0 = r0[lane], k1 = r1[lane];
        float s0 = q2.x * (b2f(k0.x) + f00) + q2.y * (b2f(k0.y) + f01);
        float s1 = q2.x * (b2f(k1.x) + f10) + q2.y * (b2f(k1.y) + f11);
        #pragma unroll
        for (int off = 32; off; off >>= 1) {
            s0 += __shfl_xor(s0, off, 64);
            s1 += __shfl_xor(s1, off, 64);
        }
        float e0 = __expf(s0 * ATT_SCALE);
        float e1 = __expf(s1 * ATT_SCALE);
        ushort2 v0 = r0[64 + lane], v1 = r1[64 + lane];
        l  += e0 + e1;
        A0 += e0 * (b2f(v0.x) + f00) + e1 * (b2f(v1.x) + f10);
        A1 += e0 * (b2f(v0.y) + f01) + e1 * (b2f(v1.y) + f11);
    }
    if (p < p1) {
        int2 se0 = csr_se[p];
        float ev0 = (lane < EDGE_DIM) ? ea[(size_t)se0.y * EDGE_DIM + lane] : 0.f;
        float f00 = 0.f, f01 = 0.f;
        #pragma unroll
        for (int j = 0; j < EDGE_DIM; ++j) {
            float a = __shfl(ev0, j, 64);
            f00 += a * w0[j]; f01 += a * w1[j];
        }
        const ushort2* r0 = (const ushort2*)(kv + (size_t)se0.x * 256);
        ushort2 k0 = r0[lane];
        float s0 = q2.x * (b2f(k0.x) + f00) + q2.y * (b2f(k0.y) + f01);
        #pragma unroll
        for (int off = 32; off; off >>= 1) s0 += __shfl_xor(s0, off, 64);
        float e0 = __expf(s0 * ATT_SCALE);
        ushort2 v0 = r0[64 + lane];
        l  += e0;
        A0 += e0 * (b2f(v0.x) + f00);
        A1 += e0 * (b2f(v0.y) + f01);
    }

    float inv = 1.f / l;
    float2* o = (float2*)&out[(size_t)node * HID + d0];
    float2 cur = *o;
    cur.x += A0 * inv;
    cur.y += A1 * inv;
    *o = cur;
}

// ---- BN stats ----
__global__ __launch_bounds__(256) void bnstats_kernel(const float* __restrict__ out,
                                                      float* __restrict__ sums,
                                                      float* __restrict__ sumsq, int N) {
    int f = threadIdx.x & 127;
    int half = threadIdx.x >> 7;
    float s = 0.f, s2 = 0.f;
    for (int r = blockIdx.x * 2 + half; r < N; r += gridDim.x * 2) {
        float h = out[(size_t)r * HID + f];
        h = h > 0.f ? h : 0.f;
        s += h; s2 += h * h;
    }
    __shared__ float ls[256], ls2[256];
    ls[threadIdx.x] = s; ls2[threadIdx.x] = s2;
    __syncthreads();
    if (half == 0) {
        atomicAdd(&sums[f], ls[f] + ls[f + 128]);
        atomicAdd(&sumsq[f], ls2[f] + ls2[f + 128]);
    }
}

__global__ void bnscale_kernel(const float* __restrict__ sums, const float* __restrict__ sumsq,
                               const float* __restrict__ gamma, const float* __restrict__ beta,
                               float* __restrict__ scale, float* __restrict__ shift, int N) {
    int f = threadIdx.x;
    if (f < HID) {
        float invN = 1.f / (float)N;
        float m = sums[f] * invN;
        float var = sumsq[f] * invN - m * m;
        float s = gamma[f] * rsqrtf(var + BN_EPS);
        scale[f] = s;
        shift[f] = beta[f] - m * s;
    }
}

__global__ __launch_bounds__(256) void bnapply_kernel(float* __restrict__ out,
                                                      const float* __restrict__ scale,
                                                      const float* __restrict__ shift, int N) {
    int idx = blockIdx.x * 256 + threadIdx.x;
    int total = N * (HID / 4);
    if (idx >= total) return;
    int f4 = (idx & 31) * 4;
    float4 v = ((const float4*)out)[idx];
    float4 o;
    float h;
    h = v.x > 0.f ? v.x : 0.f; o.x = h * scale[f4 + 0] + shift[f4 + 0];
    h = v.y > 0.f ? v.y : 0.f; o.y = h * scale[f4 + 1] + shift[f4 + 1];
    h = v.z > 0.f ? v.z : 0.f; o.z = h * scale[f4 + 2] + shift[f4 + 2];
    h = v.w > 0.f ? v.w : 0.f; o.w = h * scale[f4 + 3] + shift[f4 + 3];
    ((float4*)out)[idx] = o;
}

extern "C" void kernel_launch(void* const* d_in, const int* in_sizes, int n_in,
                              void* d_out, int out_size, void* d_ws, size_t ws_size,
                              hipStream_t stream) {
    const float* x     = (const float*)d_in[0];
    const int*   ei    = (const int*)d_in[1];
    const float* ea    = (const float*)d_in[2];
    const float* Wq    = (const float*)d_in[3];
    const float* bq    = (const float*)d_in[4];
    const float* Wk    = (const float*)d_in[5];
    const float* bk    = (const float*)d_in[6];
    const float* Wv    = (const float*)d_in[7];
    const float* bv    = (const float*)d_in[8];
    const float* We    = (const float*)d_in[9];
    const float* Wskip = (const float*)d_in[10];
    const float* bskip = (const float*)d_in[11];
    const float* gamma = (const float*)d_in[12];
    const float* beta  = (const float*)d_in[13];
    float* out = (float*)d_out;

    const int N = in_sizes[0] / HID;
    const int E = in_sizes[2] / EDGE_DIM;
    const size_t NH = (size_t)N * HID;
    const int nb = (N + 255) / 256;   // scan blocks (must be <= 256)

    char* wsb = (char*)d_ws;
    float* q_all   = (float*)wsb;                          // NH floats
    ushort_t* kv   = (ushort_t*)(wsb + NH * 4);            // N*256 ushorts (k|v bf16)
    int2* csr_se   = (int2*)(wsb + NH * 4 + (size_t)N * 512);  // E int2
    int* deg       = (int*)(csr_se + E);                   // N
    int* rowptr    = deg + N;                              // N+1
    int* partials  = rowptr + N + 1;                       // nb (<=256)
    float* sums    = (float*)(partials + 256);
    float* sumsq   = sums + HID;
    float* scale   = sumsq + HID;
    float* shift   = scale + HID;

    init_kernel<<<nb, 256, 0, stream>>>(deg, sums, sumsq, N);

    dim3 pg((N + 63) / 64, 4);
    proj_kernel<<<pg, 256, 0, stream>>>(x, Wq, bq, Wk, bk, Wv, bv, Wskip, bskip,
                                        q_all, kv, out, N);

    degree_kernel<<<(E + 255) / 256, 256, 0, stream>>>(ei, deg, E);
    scan1_kernel<<<nb, 256, 0, stream>>>(deg, rowptr, partials, N);
    scan2_kernel<<<1, 256, 0, stream>>>(partials, rowptr, nb, N);
    scan3_kernel<<<nb, 256, 0, stream>>>(rowptr, deg, partials, N);
    scatter_kernel<<<(E + 255) / 256, 256, 0, stream>>>(ei, deg, csr_se, E);

    attn_kernel<<<(N + 3) / 4, 256, 0, stream>>>(ea, We, q_all, kv, rowptr, csr_se, out, N);

    bnstats_kernel<<<1024, 256, 0, stream>>>(out, sums, sumsq, N);
    bnscale_kernel<<<1, 128, 0, stream>>>(sums, sumsq, gamma, beta, scale, shift, N);
    bnapply_kernel<<<(N * (HID / 4) + 255) / 256, 256, 0, stream>>>(out, scale, shift, N);
}

// Round 4
// 308.489 us; speedup vs baseline: 3.3870x; 1.5131x over previous
//
#include <hip/hip_runtime.h>

#define HID 128
#define EDGE_DIM 10
#define BN_EPS 1e-5f
#define ATT_SCALE 0.08838834764831845f  // 1/sqrt(128)

typedef unsigned short ushort_t;
typedef __attribute__((ext_vector_type(8))) short short8v;
typedef __attribute__((ext_vector_type(4))) float float4v;

__device__ __forceinline__ float b2f(ushort_t u) {
    return __uint_as_float(((unsigned)u) << 16);
}
__device__ __forceinline__ ushort_t f2b(float f) {   // RNE
    unsigned u = __float_as_uint(f);
    return (ushort_t)((u + 0x7FFFu + ((u >> 16) & 1u)) >> 16);
}

// ---- init: zero degree counters and BN sums ----
__global__ void init_kernel(int* __restrict__ deg, float* __restrict__ sums,
                            float* __restrict__ sumsq, int N) {
    int i = blockIdx.x * 256 + threadIdx.x;
    if (i < N) deg[i] = 0;
    if (i < HID) { sums[i] = 0.f; sumsq[i] = 0.f; }
}

// ---- convert x and the 4 weight matrices to bf16 ----
// Wb layout: [which][c][k], which: 0=q 1=k 2=v 3=skip
__global__ void convert_kernel(const float* __restrict__ x,
                               const float* __restrict__ Wq, const float* __restrict__ Wk,
                               const float* __restrict__ Wv, const float* __restrict__ Wskip,
                               ushort_t* __restrict__ xb, ushort_t* __restrict__ Wb, int N) {
    int i = blockIdx.x * 256 + threadIdx.x;
    int xcount = N * (HID / 4);
    if (i < xcount) {
        float4 v = ((const float4*)x)[i];
        ushort4 o;
        o.x = f2b(v.x); o.y = f2b(v.y); o.z = f2b(v.z); o.w = f2b(v.w);
        ((ushort4*)xb)[i] = o;
    } else {
        int j = i - xcount;
        if (j < 4 * 128 * 128 / 4) {
            int w = j >> 12;            // 4096 float4-groups per matrix
            int g = j & 4095;
            const float* W = (w == 0) ? Wq : (w == 1) ? Wk : (w == 2) ? Wv : Wskip;
            float4 v = ((const float4*)W)[g];
            ushort4 o;
            o.x = f2b(v.x); o.y = f2b(v.y); o.z = f2b(v.z); o.w = f2b(v.w);
            ((ushort4*)(Wb + (size_t)w * 128 * 128))[g] = o;
        }
    }
}

// ---- MFMA projections: block = one 16-node tile; wave w computes proj w ----
// out(proj 0) -> q_all fp32; 1 -> kv[0:128] bf16; 2 -> kv[128:256] bf16; 3 -> out fp32
__global__ __launch_bounds__(256) void mfma_proj_kernel(
    const ushort_t* __restrict__ xb, const ushort_t* __restrict__ Wb,
    const float* __restrict__ bq, const float* __restrict__ bk,
    const float* __restrict__ bv, const float* __restrict__ bskip,
    float* __restrict__ q_all, ushort_t* __restrict__ kv,
    float* __restrict__ out, int N)
{
    const int which = threadIdx.x >> 6;           // 0..3
    const int lane  = threadIdx.x & 63;
    const int n0    = blockIdx.x * 16;
    const ushort_t* W = Wb + (size_t)which * 128 * 128;
    const float* bias = (which == 0) ? bq : (which == 1) ? bk : (which == 2) ? bv : bskip;

    const int row  = lane & 15;
    const int kgrp = lane >> 4;

    int arow = n0 + row; if (arow >= N) arow = N - 1;

    float4v acc[8];
    #pragma unroll
    for (int ct = 0; ct < 8; ++ct) acc[ct] = (float4v){0.f, 0.f, 0.f, 0.f};

    #pragma unroll
    for (int kt = 0; kt < 4; ++kt) {
        const int k0 = kt * 32 + kgrp * 8;
        short8v a = *(const short8v*)&xb[(size_t)arow * HID + k0];
        #pragma unroll
        for (int ct = 0; ct < 8; ++ct) {
            short8v b = *(const short8v*)&W[(size_t)(ct * 16 + row) * HID + k0];
            acc[ct] = __builtin_amdgcn_mfma_f32_16x16x32_bf16(a, b, acc[ct], 0, 0, 0);
        }
    }

    // C/D: col = lane&15, row = (lane>>4)*4 + r
    const int col16 = lane & 15;
    const int orow  = (lane >> 4) * 4;
    float bv8[8];
    #pragma unroll
    for (int ct = 0; ct < 8; ++ct) bv8[ct] = bias[ct * 16 + col16];

    #pragma unroll
    for (int r = 0; r < 4; ++r) {
        int node = n0 + orow + r;
        if (node >= N) continue;
        #pragma unroll
        for (int ct = 0; ct < 8; ++ct) {
            float val = acc[ct][r] + bv8[ct];
            int c = ct * 16 + col16;
            if (which == 0)      q_all[(size_t)node * HID + c] = val;
            else if (which == 3) out[(size_t)node * HID + c] = val;
            else kv[(size_t)node * 256 + (which == 2 ? 128 : 0) + c] = f2b(val);
        }
    }
}

// ---- CSR build step 1: in-degree count ----
__global__ void degree_kernel(const int* __restrict__ ei, int* __restrict__ deg, int E) {
    int e = blockIdx.x * 256 + threadIdx.x;
    if (e < E) atomicAdd(&deg[ei[E + e]], 1);
}

// ---- CSR build: 3-phase parallel exclusive scan ----
__global__ __launch_bounds__(256) void scan1_kernel(const int* __restrict__ deg,
                                                    int* __restrict__ rowptr,
                                                    int* __restrict__ partials, int N) {
    int i = blockIdx.x * 256 + threadIdx.x;
    int v = (i < N) ? deg[i] : 0;
    __shared__ int sm[256];
    sm[threadIdx.x] = v;
    __syncthreads();
    for (int off = 1; off < 256; off <<= 1) {
        int t = (threadIdx.x >= off) ? sm[threadIdx.x - off] : 0;
        __syncthreads();
        sm[threadIdx.x] += t;
        __syncthreads();
    }
    if (i < N) rowptr[i] = sm[threadIdx.x] - v;
    if (threadIdx.x == 255) partials[blockIdx.x] = sm[255];
}

__global__ __launch_bounds__(256) void scan2_kernel(int* __restrict__ partials,
                                                    int* __restrict__ rowptr, int nb, int N) {
    __shared__ int sm[256];
    int v = (threadIdx.x < nb) ? partials[threadIdx.x] : 0;
    sm[threadIdx.x] = v;
    __syncthreads();
    for (int off = 1; off < 256; off <<= 1) {
        int t = (threadIdx.x >= off) ? sm[threadIdx.x - off] : 0;
        __syncthreads();
        sm[threadIdx.x] += t;
        __syncthreads();
    }
    if (threadIdx.x < nb) partials[threadIdx.x] = sm[threadIdx.x] - v;
    if (threadIdx.x == 255) rowptr[N] = sm[255];
}

__global__ __launch_bounds__(256) void scan3_kernel(int* __restrict__ rowptr,
                                                    int* __restrict__ deg,
                                                    const int* __restrict__ partials, int N) {
    int i = blockIdx.x * 256 + threadIdx.x;
    if (i < N) {
        int r = rowptr[i] + partials[blockIdx.x];
        rowptr[i] = r;
        deg[i] = r;
    }
}

// ---- CSR scatter: (src, eid) pairs into dst buckets ----
__global__ void scatter_kernel(const int* __restrict__ ei, int* __restrict__ cursor,
                               int2* __restrict__ csr_se, int E) {
    int e = blockIdx.x * 256 + threadIdx.x;
    if (e < E) {
        int src = ei[e];
        int dst = ei[E + e];
        int pos = atomicAdd(&cursor[dst], 1);
        csr_se[pos] = make_int2(src, e);
    }
}

// ---- fused attention: one wave per dst node, scalar ea loads, 4-edge unroll ----
__global__ __launch_bounds__(256) void attn_kernel(
    const float* __restrict__ ea, const float* __restrict__ We,
    const float* __restrict__ q_all, const ushort_t* __restrict__ kv,
    const int* __restrict__ rowptr, const int2* __restrict__ csr_se,
    float* __restrict__ out, int N)
{
    const int node = blockIdx.x * 4 + (threadIdx.x >> 6);
    if (node >= N) return;
    const int lane = threadIdx.x & 63;
    const int d0 = lane * 2;

    float w0[EDGE_DIM], w1[EDGE_DIM];
    #pragma unroll
    for (int j = 0; j < EDGE_DIM; ++j) {
        w0[j] = We[d0 * EDGE_DIM + j];
        w1[j] = We[(d0 + 1) * EDGE_DIM + j];
    }

    const int p0 = rowptr[node];
    const int p1 = rowptr[node + 1];
    if (p0 == p1) return;

    float2 q2 = ((const float2*)q_all)[(size_t)node * 64 + lane];

    float l = 0.f, A0 = 0.f, A1 = 0.f;
    int p = p0;
    for (; p + 4 <= p1; p += 4) {
        int src[4], eid[4];
        #pragma unroll
        for (int i = 0; i < 4; ++i) {
            int2 se = csr_se[p + i];
            src[i] = __builtin_amdgcn_readfirstlane(se.x);
            eid[i] = __builtin_amdgcn_readfirstlane(se.y);
        }
        float f0[4], f1[4];
        #pragma unroll
        for (int i = 0; i < 4; ++i) { f0[i] = 0.f; f1[i] = 0.f; }
        #pragma unroll
        for (int j = 0; j < EDGE_DIM; ++j) {
            #pragma unroll
            for (int i = 0; i < 4; ++i) {
                float a = ea[(size_t)eid[i] * EDGE_DIM + j];   // scalar (uniform) load
                f0[i] += a * w0[j];
                f1[i] += a * w1[j];
            }
        }
        ushort2 kk[4];
        #pragma unroll
        for (int i = 0; i < 4; ++i)
            kk[i] = ((const ushort2*)(kv + (size_t)src[i] * 256))[lane];
        float s[4];
        #pragma unroll
        for (int i = 0; i < 4; ++i)
            s[i] = q2.x * (b2f(kk[i].x) + f0[i]) + q2.y * (b2f(kk[i].y) + f1[i]);
        #pragma unroll
        for (int off = 32; off; off >>= 1) {
            #pragma unroll
            for (int i = 0; i < 4; ++i) s[i] += __shfl_xor(s[i], off, 64);
        }
        ushort2 vv[4];
        float ex[4];
        #pragma unroll
        for (int i = 0; i < 4; ++i) {
            ex[i] = __expf(s[i] * ATT_SCALE);
            vv[i] = ((const ushort2*)(kv + (size_t)src[i] * 256))[64 + lane];
        }
        #pragma unroll
        for (int i = 0; i < 4; ++i) {
            l  += ex[i];
            A0 += ex[i] * (b2f(vv[i].x) + f0[i]);
            A1 += ex[i] * (b2f(vv[i].y) + f1[i]);
        }
    }
    for (; p < p1; ++p) {
        int2 se = csr_se[p];
        int srcs = __builtin_amdgcn_readfirstlane(se.x);
        int eids = __builtin_amdgcn_readfirstlane(se.y);
        float f0 = 0.f, f1 = 0.f;
        #pragma unroll
        for (int j = 0; j < EDGE_DIM; ++j) {
            float a = ea[(size_t)eids * EDGE_DIM + j];
            f0 += a * w0[j];
            f1 += a * w1[j];
        }
        ushort2 k2 = ((const ushort2*)(kv + (size_t)srcs * 256))[lane];
        float s = q2.x * (b2f(k2.x) + f0) + q2.y * (b2f(k2.y) + f1);
        #pragma unroll
        for (int off = 32; off; off >>= 1) s += __shfl_xor(s, off, 64);
        float e0 = __expf(s * ATT_SCALE);
        ushort2 v2 = ((const ushort2*)(kv + (size_t)srcs * 256))[64 + lane];
        l  += e0;
        A0 += e0 * (b2f(v2.x) + f0);
        A1 += e0 * (b2f(v2.y) + f1);
    }

    float inv = 1.f / l;
    float2* o = (float2*)&out[(size_t)node * HID + d0];
    float2 cur = *o;
    cur.x += A0 * inv;
    cur.y += A1 * inv;
    *o = cur;
}

// ---- BN stats ----
__global__ __launch_bounds__(256) void bnstats_kernel(const float* __restrict__ out,
                                                      float* __restrict__ sums,
                                                      float* __restrict__ sumsq, int N) {
    int f = threadIdx.x & 127;
    int half = threadIdx.x >> 7;
    float s = 0.f, s2 = 0.f;
    for (int r = blockIdx.x * 2 + half; r < N; r += gridDim.x * 2) {
        float h = out[(size_t)r * HID + f];
        h = h > 0.f ? h : 0.f;
        s += h; s2 += h * h;
    }
    __shared__ float ls[256], ls2[256];
    ls[threadIdx.x] = s; ls2[threadIdx.x] = s2;
    __syncthreads();
    if (half == 0) {
        atomicAdd(&sums[f], ls[f] + ls[f + 128]);
        atomicAdd(&sumsq[f], ls2[f] + ls2[f + 128]);
    }
}

__global__ void bnscale_kernel(const float* __restrict__ sums, const float* __restrict__ sumsq,
                               const float* __restrict__ gamma, const float* __restrict__ beta,
                               float* __restrict__ scale, float* __restrict__ shift, int N) {
    int f = threadIdx.x;
    if (f < HID) {
        float invN = 1.f / (float)N;
        float m = sums[f] * invN;
        float var = sumsq[f] * invN - m * m;
        float s = gamma[f] * rsqrtf(var + BN_EPS);
        scale[f] = s;
        shift[f] = beta[f] - m * s;
    }
}

__global__ __launch_bounds__(256) void bnapply_kernel(float* __restrict__ out,
                                                      const float* __restrict__ scale,
                                                      const float* __restrict__ shift, int N) {
    int idx = blockIdx.x * 256 + threadIdx.x;
    int total = N * (HID / 4);
    if (idx >= total) return;
    int f4 = (idx & 31) * 4;
    float4 v = ((const float4*)out)[idx];
    float4 o;
    float h;
    h = v.x > 0.f ? v.x : 0.f; o.x = h * scale[f4 + 0] + shift[f4 + 0];
    h = v.y > 0.f ? v.y : 0.f; o.y = h * scale[f4 + 1] + shift[f4 + 1];
    h = v.z > 0.f ? v.z : 0.f; o.z = h * scale[f4 + 2] + shift[f4 + 2];
    h = v.w > 0.f ? v.w : 0.f; o.w = h * scale[f4 + 3] + shift[f4 + 3];
    ((float4*)out)[idx] = o;
}

extern "C" void kernel_launch(void* const* d_in, const int* in_sizes, int n_in,
                              void* d_out, int out_size, void* d_ws, size_t ws_size,
                              hipStream_t stream) {
    const float* x     = (const float*)d_in[0];
    const int*   ei    = (const int*)d_in[1];
    const float* ea    = (const float*)d_in[2];
    const float* Wq    = (const float*)d_in[3];
    const float* bq    = (const float*)d_in[4];
    const float* Wk    = (const float*)d_in[5];
    const float* bk    = (const float*)d_in[6];
    const float* Wv    = (const float*)d_in[7];
    const float* bv    = (const float*)d_in[8];
    const float* We    = (const float*)d_in[9];
    const float* Wskip = (const float*)d_in[10];
    const float* bskip = (const float*)d_in[11];
    const float* gamma = (const float*)d_in[12];
    const float* beta  = (const float*)d_in[13];
    float* out = (float*)d_out;

    const int N = in_sizes[0] / HID;
    const int E = in_sizes[2] / EDGE_DIM;
    const size_t NH = (size_t)N * HID;
    const int nb = (N + 255) / 256;

    char* wsb = (char*)d_ws;
    float* q_all   = (float*)wsb;                               // NH f32
    ushort_t* kv   = (ushort_t*)(wsb + NH * 4);                 // N*256 bf16
    ushort_t* xb   = kv + (size_t)N * 256;                      // NH bf16
    ushort_t* Wb   = xb + NH;                                   // 4*128*128 bf16
    int2* csr_se   = (int2*)(Wb + 4 * 128 * 128);               // E int2
    int* deg       = (int*)(csr_se + E);                        // N
    int* rowptr    = deg + N;                                   // N+1
    int* partials  = rowptr + N + 1;                            // <=256
    float* sums    = (float*)(partials + 256);
    float* sumsq   = sums + HID;
    float* scale   = sumsq + HID;
    float* shift   = scale + HID;

    init_kernel<<<nb, 256, 0, stream>>>(deg, sums, sumsq, N);

    int ccount = N * (HID / 4) + 4 * 128 * 128 / 4;
    convert_kernel<<<(ccount + 255) / 256, 256, 0, stream>>>(x, Wq, Wk, Wv, Wskip, xb, Wb, N);

    mfma_proj_kernel<<<(N + 15) / 16, 256, 0, stream>>>(xb, Wb, bq, bk, bv, bskip,
                                                        q_all, kv, out, N);

    degree_kernel<<<(E + 255) / 256, 256, 0, stream>>>(ei, deg, E);
    scan1_kernel<<<nb, 256, 0, stream>>>(deg, rowptr, partials, N);
    scan2_kernel<<<1, 256, 0, stream>>>(partials, rowptr, nb, N);
    scan3_kernel<<<nb, 256, 0, stream>>>(rowptr, deg, partials, N);
    scatter_kernel<<<(E + 255) / 256, 256, 0, stream>>>(ei, deg, csr_se, E);

    attn_kernel<<<(N + 3) / 4, 256, 0, stream>>>(ea, We, q_all, kv, rowptr, csr_se, out, N);

    bnstats_kernel<<<1024, 256, 0, stream>>>(out, sums, sumsq, N);
    bnscale_kernel<<<1, 128, 0, stream>>>(sums, sumsq, gamma, beta, scale, shift, N);
    bnapply_kernel<<<(N * (HID / 4) + 255) / 256, 256, 0, stream>>>(out, scale, shift, N);
}